// Round 2
// baseline (1699.953 us; speedup 1.0000x reference)
//
#include <hip/hip_runtime.h>
#include <math.h>

// Problem constants
#define T_SEQ 300
#define E_DIM 300
#define H_DIM 512
#define G4    2048          // 4*H
#define NEXPT 13
#define NBLK  64            // persistent blocks; block b owns cells 8b..8b+7
#define NTHR  512

__device__ __forceinline__ float sigm(float x) { return 1.0f / (1.0f + __expf(-x)); }
__device__ __forceinline__ float ftanh(float x) {
  x = fminf(15.0f, fmaxf(-15.0f, x));
  float u = __expf(2.0f * x);
  return (u - 1.0f) / (u + 1.0f);
}

// ---------------------------------------------------------------------------
// Kernel 1: pre-gates, coalesced. grid = 13 experts * 32 chunks (64 rows),
// 256 threads = 64 rows x 4 k-quarters. A 4-lane cluster reads one W_ih row:
// lane kq reads float4 k4 = kq + 4*i  -> 64B contiguous per cluster
// (16 cache lines per wave instruction instead of 64). 8 timesteps staged in
// LDS per pass; butterfly-reduce over the 2 kq bits gives every lane all 8
// partial sums, lanes write s = kq and kq+4.
// Output layout matches LSTM reader: pg[t*2048 + b*32 + q*8 + p]
// where global gate row r = q*512 + 8b + p.
// ---------------------------------------------------------------------------
__global__ void __launch_bounds__(256) pregates_kernel(
    const int* __restrict__ x, const int* __restrict__ tags,
    const float* __restrict__ emb, const float* __restrict__ W_ih,
    const float* __restrict__ b_ih, const float* __restrict__ b_hh,
    float* __restrict__ pg)
{
  const int e     = blockIdx.x >> 5;   // expert 0..12
  const int chunk = blockIdx.x & 31;   // 0..31
  const int tid   = threadIdx.x;
  const int r_l   = tid >> 2;          // 0..63
  const int kq    = tid & 3;           // 0..3
  const int row   = chunk * 64 + r_l;  // gate row 0..2047

  __shared__ int tags_l[T_SEQ];
  __shared__ int list[T_SEQ];
  __shared__ int nsh;
  __shared__ int xv[8];
  __shared__ __align__(16) float embL[8][E_DIM];

  for (int i = tid; i < T_SEQ; i += 256) tags_l[i] = tags[i];
  __syncthreads();
  if (tid == 0) {
    int n = 0;
    for (int t = 0; t < T_SEQ; ++t) if (tags_l[t] == e) list[n++] = t;
    nsh = n;
  }
  __syncthreads();
  const int n = nsh;
  const float bias = b_ih[e * G4 + row] + b_hh[e * G4 + row];
  const float4* wrow = (const float4*)(W_ih + ((size_t)e * G4 + row) * E_DIM);

  // precompute permuted output base for this row
  const int q = row >> 9, c = row & 511;
  const int obase = (c >> 3) * 32 + q * 8 + (c & 7);

  for (int it = 0; it < n; it += 8) {
    if (tid < 8 && it + tid < n) xv[tid] = x[list[it + tid]];
    __syncthreads();
    for (int idx = tid; idx < 8 * E_DIM; idx += 256) {
      int rs = idx / E_DIM, k = idx - rs * E_DIM;
      if (it + rs < n) embL[rs][k] = emb[(size_t)xv[rs] * E_DIM + k];
    }
    __syncthreads();

    float acc[8] = {0.f,0.f,0.f,0.f,0.f,0.f,0.f,0.f};
    #pragma unroll
    for (int i = 0; i < 19; ++i) {
      int k4 = kq + 4 * i;
      if (k4 < 75) {
        float4 w = wrow[k4];
        #pragma unroll
        for (int s = 0; s < 8; ++s) {
          float4 a = *(const float4*)&embL[s][k4 * 4];
          acc[s] += w.x * a.x + w.y * a.y + w.z * a.z + w.w * a.w;
        }
      }
    }
    #pragma unroll
    for (int s = 0; s < 8; ++s) {
      acc[s] += __shfl_xor(acc[s], 1);
      acc[s] += __shfl_xor(acc[s], 2);
    }
    #pragma unroll
    for (int s0 = 0; s0 < 2; ++s0) {
      int s = kq + 4 * s0;
      if (it + s < n) {
        int t = list[it + s];
        pg[t * G4 + obase] = acc[s] + bias;
      }
    }
    __syncthreads();
  }
}

// ---------------------------------------------------------------------------
// Kernel 2: persistent sequential LSTM. 64 blocks x 512 threads (cooperative).
// Block b owns cells 8b..8b+7 -> rows q*512 + 8b + p (q=0..3 gates, p=0..7).
// Thread = (row_local = tid>>4 in 0..31, lane_k = tid&15, 32 k each).
// Cross-block h exchange: 8B relaxed agent atomics packing (h_bits<<32)|step,
// double-buffered on t&1; one slot per thread (512 slots). W_hh + pg loads
// are issued BEFORE the poll so L2/L3 latency hides under the spin.
// ---------------------------------------------------------------------------
__global__ void __launch_bounds__(NTHR) lstm_kernel(
    const int* __restrict__ tags, const float* __restrict__ h0,
    const float* __restrict__ c0, const float* __restrict__ W_hh,
    const float* __restrict__ fc_w, const float* __restrict__ fc_b,
    const float* __restrict__ pg, unsigned long long* __restrict__ hbuf,
    float* __restrict__ out)
{
  const int b = blockIdx.x, tid = threadIdx.x;
  const int row_local = tid >> 4;       // 0..31  (= q*8 + p)
  const int lane_k    = tid & 15;       // 0..15
  const int q = row_local >> 3, p = row_local & 7;
  const int rowG = q * H_DIM + 8 * b + p;

  __shared__ int tags_l[T_SEQ];
  __shared__ __align__(16) float h_lds[2][H_DIM];
  __shared__ float gates_l[32];
  __shared__ float pg_l[32];
  __shared__ float red[8];

  for (int i = tid; i < T_SEQ; i += NTHR) tags_l[i] = tags[i];
  float c_r = 0.f, h_r = 0.f;
  if (tid < 8) c_r = c0[8 * b + tid];
  __syncthreads();

  for (int t = 0; t < T_SEQ; ++t) {
    const int e = tags_l[t];
    // Prefetch weights + pre-gate before polling (addresses depend only on
    // tags): their L2/L3 latency overlaps the spin-wait below.
    const float4* wr =
        (const float4*)(W_hh + ((size_t)e * G4 + rowG) * H_DIM) + lane_k * 8;
    float4 w0 = wr[0], w1 = wr[1], w2 = wr[2], w3 = wr[3];
    float4 w4 = wr[4], w5 = wr[5], w6 = wr[6], w7 = wr[7];
    float pgv = 0.0f;
    if (tid < 32) pgv = pg[t * G4 + b * 32 + tid];

    float* hl = h_lds[t & 1];
    if (t == 0) {
      hl[tid] = h0[tid];
    } else {
      unsigned long long* src = hbuf + (size_t)((t - 1) & 1) * H_DIM + tid;
      const unsigned tag = (unsigned)t;
      unsigned long long v;
      do { v = __hip_atomic_load(src, __ATOMIC_RELAXED, __HIP_MEMORY_SCOPE_AGENT); } while ((unsigned)v != tag);
      hl[tid] = __uint_as_float((unsigned)(v >> 32));
    }
    __syncthreads();   // barrier A: h staged

    const float4* hv = (const float4*)hl + lane_k * 8;
    float4 a0 = hv[0], a1 = hv[1], a2 = hv[2], a3 = hv[3];
    float4 a4 = hv[4], a5 = hv[5], a6 = hv[6], a7 = hv[7];
    float acc = w0.x*a0.x + w0.y*a0.y + w0.z*a0.z + w0.w*a0.w
              + w1.x*a1.x + w1.y*a1.y + w1.z*a1.z + w1.w*a1.w
              + w2.x*a2.x + w2.y*a2.y + w2.z*a2.z + w2.w*a2.w
              + w3.x*a3.x + w3.y*a3.y + w3.z*a3.z + w3.w*a3.w
              + w4.x*a4.x + w4.y*a4.y + w4.z*a4.z + w4.w*a4.w
              + w5.x*a5.x + w5.y*a5.y + w5.z*a5.z + w5.w*a5.w
              + w6.x*a6.x + w6.y*a6.y + w6.z*a6.z + w6.w*a6.w
              + w7.x*a7.x + w7.y*a7.y + w7.z*a7.z + w7.w*a7.w;
    #pragma unroll
    for (int m = 8; m >= 1; m >>= 1) acc += __shfl_xor(acc, m);
    if (lane_k == 0) gates_l[row_local] = acc;
    if (tid < 32) pg_l[tid] = pgv;
    __syncthreads();   // barrier B: gates ready

    if (tid < 8) {
      float iv = sigm (gates_l[ 0 + tid] + pg_l[ 0 + tid]);
      float fv = sigm (gates_l[ 8 + tid] + pg_l[ 8 + tid]);
      float gv = ftanh(gates_l[16 + tid] + pg_l[16 + tid]);
      float ov = sigm (gates_l[24 + tid] + pg_l[24 + tid]);
      c_r = fv * c_r + iv * gv;
      h_r = ov * ftanh(c_r);
      unsigned long long pv =
          ((unsigned long long)__float_as_uint(h_r) << 32) | (unsigned)(t + 1);
      __hip_atomic_store(hbuf + (size_t)(t & 1) * H_DIM + 8 * b + tid, pv,
                         __ATOMIC_RELAXED, __HIP_MEMORY_SCOPE_AGENT);
    }
    // No loop-end barrier needed: h_lds is parity double-buffered and the two
    // barriers bound intra-block skew to < 1 step.
  }

  if (tid < 8) {
    out[1   + 8 * b + tid] = h_r;   // h slice
    out[513 + 8 * b + tid] = c_r;   // c slice
  }

  if (b == 0) {  // final scalar: sigmoid(h(T) . fc_w + fc_b)
    unsigned long long* src = hbuf + (size_t)((T_SEQ - 1) & 1) * H_DIM + tid;
    unsigned long long v;
    do { v = __hip_atomic_load(src, __ATOMIC_RELAXED, __HIP_MEMORY_SCOPE_AGENT); } while ((unsigned)v != (unsigned)T_SEQ);
    float a = __uint_as_float((unsigned)(v >> 32)) * fc_w[tid];
    #pragma unroll
    for (int m = 32; m >= 1; m >>= 1) a += __shfl_xor(a, m);
    if ((tid & 63) == 0) red[tid >> 6] = a;
    __syncthreads();
    if (tid == 0) {
      float s = fc_b[0];
      #pragma unroll
      for (int i = 0; i < 8; ++i) s += red[i];
      out[0] = sigm(s);
    }
  }
}

// ---------------------------------------------------------------------------
extern "C" void kernel_launch(void* const* d_in, const int* in_sizes, int n_in,
                              void* d_out, int out_size, void* d_ws, size_t ws_size,
                              hipStream_t stream) {
  const int*   x    = (const int*)d_in[0];
  const int*   tags = (const int*)d_in[1];
  const float* h0   = (const float*)d_in[2];
  const float* c0   = (const float*)d_in[3];
  const float* emb  = (const float*)d_in[4];
  const float* W_ih = (const float*)d_in[5];
  const float* W_hh = (const float*)d_in[6];
  const float* b_ih = (const float*)d_in[7];
  const float* b_hh = (const float*)d_in[8];
  const float* fc_w = (const float*)d_in[9];
  const float* fc_b = (const float*)d_in[10];
  float* out = (float*)d_out;

  // Workspace: pre-gates (300*2048 fp32 = 2.4 MB), then h exchange buffer
  // (2*512 u64). Poison 0xAA each launch == invalid tag, by design.
  float* pg = (float*)d_ws;
  unsigned long long* hbuf =
      (unsigned long long*)((char*)d_ws + (size_t)T_SEQ * G4 * sizeof(float));

  pregates_kernel<<<dim3(NEXPT * 32), dim3(256), 0, stream>>>(
      x, tags, emb, W_ih, b_ih, b_hh, pg);

  void* args[] = { (void*)&tags, (void*)&h0, (void*)&c0, (void*)&W_hh,
                   (void*)&fc_w, (void*)&fc_b, (void*)&pg, (void*)&hbuf,
                   (void*)&out };
  hipLaunchCooperativeKernel((const void*)lstm_kernel, dim3(NBLK), dim3(NTHR),
                             args, 0, stream);
}